// Round 4
// baseline (411.782 us; speedup 1.0000x reference)
//
#include <hip/hip_runtime.h>
#include <hip/hip_bf16.h>
#include <math.h>

typedef short short8 __attribute__((ext_vector_type(8)));
typedef float f32x4 __attribute__((ext_vector_type(4)));

#define NROW 4096
#define DIM  128
#define NCLS 64
#define CCAP 512
#define MAXM 128
#define GRID 1024
#define NTILE 2080   // 64*65/2 upper-tri 64x64 tiles

typedef __attribute__((address_space(3))) unsigned lds_u32;
typedef const __attribute__((address_space(1))) unsigned glb_u32;

__device__ __forceinline__ void gload16(const void* g, void* lds) {
    // 16B/lane; LDS dest = wave-uniform base + lane*16, global src per-lane
    __builtin_amdgcn_global_load_lds((glb_u32*)g, (lds_u32*)lds, 16, 0, 0);
}

__device__ __forceinline__ unsigned short f2bf(float f) {
    unsigned u = __builtin_bit_cast(unsigned, f);
    unsigned r = (u + 0x7fffu + ((u >> 16) & 1u)) >> 16;   // RNE
    return (unsigned short)r;
}

// device-wide barrier: all GRID blocks co-resident by construction
__device__ __forceinline__ void devbar(unsigned* p, unsigned target) {
    __syncthreads();
    __threadfence();                                   // release: L2 writeback
    if (threadIdx.x == 0) {
        __hip_atomic_fetch_add(p, 1u, __ATOMIC_ACQ_REL, __HIP_MEMORY_SCOPE_AGENT);
        unsigned v;
        do {
            v = __hip_atomic_load(p, __ATOMIC_ACQUIRE, __HIP_MEMORY_SCOPE_AGENT);
            if (v < target) __builtin_amdgcn_s_sleep(2);
        } while (v < target);
    }
    __syncthreads();
    __threadfence();                                   // acquire: L1/L2 invalidate
}

struct P1 {
    unsigned short tA[64 * 128];
    unsigned short tB[64 * 128];
    float sqi[64], sqj[64], cacc[4][64];
    int   ti[64], tj[64];
};
struct P2 {
    unsigned short tX[MAXM * DIM];
    float sqg[MAXM], rng[MAXM], red[16];
    int   idx[MAXM];
};

__global__ __launch_bounds__(256, 4) void fused_kernel(
        const float* __restrict__ X, const int* __restrict__ tgt,
        unsigned short* __restrict__ Xb, float* __restrict__ sq, float* __restrict__ rn,
        float* __restrict__ acc, unsigned* __restrict__ tick, unsigned* __restrict__ bar,
        int* __restrict__ ccnt, int* __restrict__ list, float* __restrict__ out)
{
    __shared__ union U { P1 p1; P2 p2; } sm;
    const int t = threadIdx.x;
    const int w = t >> 6, l = t & 63, lr = l & 15, lg = l >> 4;
    const int b = blockIdx.x;

    // ================= phase 0: prep + scatter (4 rows per block) =================
    if (t < 128) {
        int row = b * 4 + (t >> 5);
        int c = t & 31;
        float4 v = *reinterpret_cast<const float4*>(X + (size_t)row * DIM + c * 4);
        float p = v.x * v.x + v.y * v.y + v.z * v.z + v.w * v.w;
        p += __shfl_xor(p, 16, 32);
        p += __shfl_xor(p, 8, 32);
        p += __shfl_xor(p, 4, 32);
        p += __shfl_xor(p, 2, 32);
        p += __shfl_xor(p, 1, 32);
        ushort4 h;
        h.x = f2bf(v.x); h.y = f2bf(v.y); h.z = f2bf(v.z); h.w = f2bf(v.w);
        *reinterpret_cast<ushort4*>(Xb + (size_t)row * DIM + c * 4) = h;
        if (c == 0) { sq[row] = p; rn[row] = 0.0f; }
    } else if (t < 132) {
        int row = b * 4 + (t - 128);
        int cls = tgt[row];
        int p = atomicAdd(&ccnt[cls], 1);
        if (p < CCAP) list[cls * CCAP + p] = row;
    }
    devbar(&bar[0], GRID);

    // ================= phase 1: row_neg over upper-tri tiles =================
    for (int k = b; k < NTILE; k += GRID) {
        // map linear k -> (bi, bj), bi <= bj ; off(r) = r*64 - r*(r-1)/2
        int bi = (int)(64.5f - sqrtf(64.5f * 64.5f - 2.0f * (float)k));
        if (bi < 0) bi = 0; if (bi > 63) bi = 63;
        while (bi < 63 && ((bi + 1) * 64 - (((bi + 1) * bi) >> 1)) <= k) ++bi;
        while (bi > 0 && (bi * 64 - ((bi * (bi - 1)) >> 1)) > k) --bi;
        int bj = bi + (k - (bi * 64 - ((bi * (bi - 1)) >> 1)));
        const int gib = bi * 64, gjb = bj * 64;

        __syncthreads();   // previous iteration's LDS readers done
        #pragma unroll
        for (int kk = 0; kk < 4; ++kk) {
            int q = w * 4 + kk;
            int row = q * 4 + (l >> 4);
            int sc = (l & 15) ^ (row & 7);              // inverse-swizzled source chunk
            gload16(Xb + (size_t)(gib + row) * DIM + sc * 8, &sm.p1.tA[q * 512]);
            gload16(Xb + (size_t)(gjb + row) * DIM + sc * 8, &sm.p1.tB[q * 512]);
        }
        if (t < 64)       { sm.p1.sqi[t] = sq[gib + t]; sm.p1.ti[t] = tgt[gib + t]; }
        else if (t < 128) { int u = t - 64; sm.p1.sqj[u] = sq[gjb + u]; sm.p1.tj[u] = tgt[gjb + u]; }
        __syncthreads();

        const int arow = w * 16 + lr;
        f32x4 C[4] = {};
        #pragma unroll
        for (int ks = 0; ks < 4; ++ks) {
            int c = ks * 4 + lg;
            short8 a = *reinterpret_cast<const short8*>(&sm.p1.tA[arow * 128 + ((c ^ (arow & 7)) * 8)]);
            #pragma unroll
            for (int fj = 0; fj < 4; ++fj) {
                int brow = fj * 16 + lr;
                short8 bb = *reinterpret_cast<const short8*>(&sm.p1.tB[brow * 128 + ((c ^ (brow & 7)) * 8)]);
                C[fj] = __builtin_amdgcn_mfma_f32_16x16x32_bf16(a, bb, C[fj], 0, 0, 0);
            }
        }

        // C[fj][r]: i = gib + w*16 + lg*4 + r, j = gjb + fj*16 + lr
        const int ibase = w * 16 + lg * 4;
        float sqi[4]; int ti[4];
        #pragma unroll
        for (int r = 0; r < 4; ++r) { sqi[r] = sm.p1.sqi[ibase + r]; ti[r] = sm.p1.ti[ibase + r]; }

        float racc[4] = {0.f, 0.f, 0.f, 0.f};
        float cacc[4] = {0.f, 0.f, 0.f, 0.f};
        #pragma unroll
        for (int fj = 0; fj < 4; ++fj) {
            int jl = fj * 16 + lr;
            float sqj = sm.p1.sqj[jl];
            int   tj  = sm.p1.tj[jl];
            int   gj  = gjb + jl;
            #pragma unroll
            for (int r = 0; r < 4; ++r) {
                int gi = gib + ibase + r;
                float d2 = fmaxf(sqi[r] + sqj - 2.0f * C[fj][r], 0.0f);
                float dist = __builtin_amdgcn_sqrtf(d2);
                float e = __expf(1.0f - dist);
                bool valid = (gi < gj) && (ti[r] != tj) && (d2 > 0.0f);
                e = valid ? e : 0.0f;
                racc[r] += e;
                cacc[fj] += e;
            }
        }
        #pragma unroll
        for (int r = 0; r < 4; ++r) {
            racc[r] += __shfl_xor(racc[r], 1);
            racc[r] += __shfl_xor(racc[r], 2);
            racc[r] += __shfl_xor(racc[r], 4);
            racc[r] += __shfl_xor(racc[r], 8);
        }
        if (lr == 0) {
            #pragma unroll
            for (int r = 0; r < 4; ++r) atomicAdd(&rn[gib + ibase + r], racc[r]);
        }
        #pragma unroll
        for (int fj = 0; fj < 4; ++fj) {
            cacc[fj] += __shfl_xor(cacc[fj], 16);
            cacc[fj] += __shfl_xor(cacc[fj], 32);
        }
        if (lg == 0) {
            #pragma unroll
            for (int fj = 0; fj < 4; ++fj) sm.p1.cacc[w][fj * 16 + lr] = cacc[fj];
        }
        __syncthreads();
        if (t < 64) {
            float cs = sm.p1.cacc[0][t] + sm.p1.cacc[1][t] + sm.p1.cacc[2][t] + sm.p1.cacc[3][t];
            if (cs != 0.0f) atomicAdd(&rn[gjb + t], cs);
        }
    }
    devbar(&bar[1], GRID);

    // ================= phase 2: per-class positive loss (blocks 0..63) =================
    if (b < NCLS) {
        const int c = b;
        int m = ccnt[c]; if (m > CCAP) m = CCAP;
        const int mm = m < MAXM ? m : MAXM;
        const int nfj = (mm + 15) >> 4;

        if (t < MAXM) sm.p2.idx[t] = (t < mm) ? list[c * CCAP + t] : 0;
        __syncthreads();
        if (t < MAXM) {
            int ri = sm.p2.idx[t];
            sm.p2.sqg[t] = (t < mm) ? sq[ri] : 0.0f;
            sm.p2.rng[t] = (t < mm) ? rn[ri] : 0.0f;
        }
        #pragma unroll
        for (int kk = 0; kk < 8; ++kk) {
            int q = w * 8 + kk;
            int row = q * 4 + (l >> 4);
            int sc = (l & 15) ^ (row & 7);
            gload16(Xb + (size_t)sm.p2.idx[row] * DIM + sc * 8, &sm.p2.tX[q * 512]);
        }
        __syncthreads();

        float csum = 0.0f, cpairs = 0.0f;
        #pragma unroll
        for (int fi = 0; fi < 2; ++fi) {
            if (w * 32 + fi * 16 < mm) {                // wave-uniform guard
                f32x4 C[8] = {};
                const int arow = w * 32 + fi * 16 + lr;
                #pragma unroll
                for (int ks = 0; ks < 4; ++ks) {
                    int cb = ks * 4 + lg;
                    short8 a = *reinterpret_cast<const short8*>(&sm.p2.tX[arow * DIM + ((cb ^ (arow & 7)) * 8)]);
                    #pragma unroll
                    for (int fj = 0; fj < 8; ++fj) {
                        if (fj < nfj) {
                            int brow = fj * 16 + lr;
                            short8 bb = *reinterpret_cast<const short8*>(&sm.p2.tX[brow * DIM + ((cb ^ (brow & 7)) * 8)]);
                            C[fj] = __builtin_amdgcn_mfma_f32_16x16x32_bf16(a, bb, C[fj], 0, 0, 0);
                        }
                    }
                }
                #pragma unroll
                for (int fj = 0; fj < 8; ++fj) {
                    if (fj < nfj) {
                        int q = fj * 16 + lr;
                        #pragma unroll
                        for (int r = 0; r < 4; ++r) {
                            int p = w * 32 + fi * 16 + lg * 4 + r;
                            if (q < mm && p < q) {
                                float d2 = fmaxf(sm.p2.sqg[p] + sm.p2.sqg[q] - 2.0f * C[fj][r], 0.0f);
                                float dist = __builtin_amdgcn_sqrtf(d2);
                                float J = __logf(sm.p2.rng[p] + sm.p2.rng[q]) + dist;
                                if (J > 0.0f) csum += J * J;
                                cpairs += 1.0f;
                            }
                        }
                    }
                }
            }
        }

        // correctness fallback for improbably large classes (fp32, never hot)
        if (m > MAXM) {
            for (int q = MAXM; q < m; ++q) {
                int rq = list[c * CCAP + q];
                float sqq = sq[rq], rnq = rn[rq];
                for (int p = t; p < q; p += 256) {
                    int rp = list[c * CCAP + p];
                    const float4* xa = reinterpret_cast<const float4*>(X + (size_t)rp * DIM);
                    const float4* xb = reinterpret_cast<const float4*>(X + (size_t)rq * DIM);
                    float d = 0.0f;
                    for (int kq = 0; kq < 32; ++kq) {
                        float4 av = xa[kq], bv = xb[kq];
                        d += av.x * bv.x + av.y * bv.y + av.z * bv.z + av.w * bv.w;
                    }
                    float d2 = fmaxf(sq[rp] + sqq - 2.0f * d, 0.0f);
                    float dist = __builtin_amdgcn_sqrtf(d2);
                    float J = __logf(rn[rp] + rnq) + dist;
                    if (J > 0.0f) csum += J * J;
                    cpairs += 1.0f;
                }
            }
        }

        #pragma unroll
        for (int mr = 1; mr < 64; mr <<= 1) {
            csum   += __shfl_xor(csum, mr);
            cpairs += __shfl_xor(cpairs, mr);
        }
        if (l == 0) { sm.p2.red[w] = csum; sm.p2.red[8 + w] = cpairs; }
        __syncthreads();
        if (t == 0) {
            float bs = sm.p2.red[0] + sm.p2.red[1] + sm.p2.red[2] + sm.p2.red[3];
            float bc = sm.p2.red[8] + sm.p2.red[9] + sm.p2.red[10] + sm.p2.red[11];
            atomicAdd(&acc[0], bs);
            atomicAdd(&acc[1], bc);
            __threadfence();
            unsigned old = atomicAdd(tick, 1u);
            if (old == NCLS - 1) {
                float s  = atomicAdd(&acc[0], 0.0f);
                float n2 = atomicAdd(&acc[1], 0.0f);
                out[0] = s / (2.0f * n2);              // len_p = 2 * upper-tri count
            }
        }
    }
}

extern "C" void kernel_launch(void* const* d_in, const int* in_sizes, int n_in,
                              void* d_out, int out_size, void* d_ws, size_t ws_size,
                              hipStream_t stream)
{
    const float* X  = (const float*)d_in[0];
    const int* tgt  = (const int*)d_in[1];
    float* out      = (float*)d_out;

    char* ws = (char*)d_ws;
    unsigned short* Xb = (unsigned short*)ws;                       // 1 MB
    float* sq   = (float*)(ws + (size_t)NROW * DIM * 2);            // 16 KB
    float* rn   = sq + NROW;                                        // 16 KB
    char* ctrl  = (char*)(rn + NROW);                               // control block (zeroed)
    float*    acc  = (float*)ctrl;                                  // [0..1]
    unsigned* tick = (unsigned*)(acc + 2);                          // [2]
    unsigned* bar  = tick + 1;                                      // [3..4]
    int*      ccnt = (int*)(bar + 2);                               // 64 ints
    int*      list = (int*)(ctrl + 1024);                           // 128 KB

    hipMemsetAsync(ctrl, 0, 1024, stream);
    fused_kernel<<<GRID, 256, 0, stream>>>(X, tgt, Xb, sq, rn, acc, tick, bar, ccnt, list, out);
}

// Round 5
// 42.842 us; speedup vs baseline: 9.6116x; 9.6116x over previous
//
#include <hip/hip_runtime.h>
#include <hip/hip_bf16.h>
#include <math.h>

typedef short short8 __attribute__((ext_vector_type(8)));
typedef float f32x4 __attribute__((ext_vector_type(4)));

#define NROW 4096
#define DIM  128
#define NCLS 64
#define CCAP 512
#define MAXM 128
#define NBT  32      // number of 128-row tile blocks
#define NTILE 528    // NBT*(NBT+1)/2 upper-tri tiles

typedef __attribute__((address_space(3))) unsigned lds_u32;
typedef const __attribute__((address_space(1))) unsigned glb_u32;

__device__ __forceinline__ void gload16(const void* g, void* lds) {
    // 16B/lane; LDS dest = wave-uniform base + lane*16, global src per-lane
    __builtin_amdgcn_global_load_lds((glb_u32*)g, (lds_u32*)lds, 16, 0, 0);
}

__device__ __forceinline__ unsigned short f2bf(float f) {
    unsigned u = __builtin_bit_cast(unsigned, f);
    unsigned r = (u + 0x7fffu + ((u >> 16) & 1u)) >> 16;   // RNE
    return (unsigned short)r;
}

// ---- prep: fp32 row norms, bf16 copy, zero rn/acc/tick/class counters ----
__global__ __launch_bounds__(256) void prep_kernel(const float* __restrict__ X,
        unsigned short* __restrict__ Xb, float* __restrict__ sq,
        float* __restrict__ rn, float* __restrict__ acc,
        unsigned* __restrict__ tick, int* __restrict__ ccnt)
{
    int t = threadIdx.x;
    int row = blockIdx.x * 8 + (t >> 5);
    int c = t & 31;
    float4 v = *reinterpret_cast<const float4*>(X + (size_t)row * DIM + c * 4);
    float p = v.x * v.x + v.y * v.y + v.z * v.z + v.w * v.w;
    p += __shfl_xor(p, 16, 32);
    p += __shfl_xor(p, 8, 32);
    p += __shfl_xor(p, 4, 32);
    p += __shfl_xor(p, 2, 32);
    p += __shfl_xor(p, 1, 32);
    ushort4 h;
    h.x = f2bf(v.x); h.y = f2bf(v.y); h.z = f2bf(v.z); h.w = f2bf(v.w);
    *reinterpret_cast<ushort4*>(Xb + (size_t)row * DIM + c * 4) = h;
    if (c == 0) { sq[row] = p; rn[row] = 0.0f; }
    if (blockIdx.x == 0) {
        if (t < NCLS) ccnt[t] = 0;
        if (t == 64) { acc[0] = 0.0f; acc[1] = 0.0f; }
        if (t == 65) tick[0] = 0u;
    }
}

// ---- row_neg: 128x128 upper-tri tiles, exact enumeration, gload_lds staging ----
// diagonal blocks (bi==bj) stage A only and also scatter rows into class lists
__global__ __launch_bounds__(512, 4) void rowneg_kernel(
        const unsigned short* __restrict__ Xb, const float* __restrict__ sq,
        const int* __restrict__ tgt, float* __restrict__ rn,
        int* __restrict__ ccnt, int* __restrict__ list)
{
    const int t = threadIdx.x;
    const int w = t >> 6, l = t & 63, lr = l & 15, lg = l >> 4;

    // invert triangular index: k -> (bi, bj), bi <= bj, off(bi)=bi*32-bi(bi-1)/2
    const int k = blockIdx.x;
    int bi = (int)(32.5f - sqrtf(32.5f * 32.5f - 2.0f * (float)k));
    if (bi < 0) bi = 0; if (bi > NBT - 1) bi = NBT - 1;
    while (bi < NBT - 1 && ((bi + 1) * NBT - (((bi + 1) * bi) >> 1)) <= k) ++bi;
    while (bi > 0 && (bi * NBT - ((bi * (bi - 1)) >> 1)) > k) --bi;
    const int bj = bi + (k - (bi * NBT - ((bi * (bi - 1)) >> 1)));
    const int gib = bi * 128, gjb = bj * 128;
    const bool diag = (bi == bj);

    __shared__ __align__(16) unsigned short tA[128 * 128];
    __shared__ __align__(16) unsigned short tB[128 * 128];
    __shared__ float s_sqi[128], s_sqj[128];
    __shared__ float s_cacc[8][128];
    __shared__ int   s_ti[128], s_tj[128];

    // stage: 32 chunks of 1KB each for tA (and tB unless diagonal)
    #pragma unroll
    for (int kk = 0; kk < 4; ++kk) {
        int q = w * 4 + kk;
        int row = q * 4 + (l >> 4);
        int sc = (l & 15) ^ (row & 7);                  // inverse-swizzled source
        gload16(Xb + (size_t)(gib + row) * DIM + sc * 8, &tA[q * 512]);
        if (!diag)
            gload16(Xb + (size_t)(gjb + row) * DIM + sc * 8, &tB[q * 512]);
    }
    if (t < 128)      { s_sqi[t] = sq[gib + t]; s_ti[t] = tgt[gib + t]; }
    else if (t < 256) { int u = t - 128; s_sqj[u] = sq[gjb + u]; s_tj[u] = tgt[gjb + u]; }
    else if (diag && t < 384) {                          // embedded class scatter
        int row = gib + (t - 256);
        int cls = tgt[row];
        int p = atomicAdd(&ccnt[cls], 1);
        if (p < CCAP) list[cls * CCAP + p] = row;
    }
    __syncthreads();

    const unsigned short* tBp = diag ? tA : tB;
    const int arow = w * 16 + lr;

    f32x4 C[8] = {};
    #pragma unroll
    for (int ks = 0; ks < 4; ++ks) {
        int c = ks * 4 + lg;
        short8 a = *reinterpret_cast<const short8*>(&tA[arow * 128 + ((c ^ (arow & 7)) * 8)]);
        #pragma unroll
        for (int fj = 0; fj < 8; ++fj) {
            int brow = fj * 16 + lr;
            short8 bb = *reinterpret_cast<const short8*>(&tBp[brow * 128 + ((c ^ (brow & 7)) * 8)]);
            C[fj] = __builtin_amdgcn_mfma_f32_16x16x32_bf16(a, bb, C[fj], 0, 0, 0);
        }
    }

    // C[fj][r]: i = gib + w*16 + lg*4 + r, j = gjb + fj*16 + lr
    const int ibase = w * 16 + lg * 4;
    float sqi[4]; int ti[4];
    #pragma unroll
    for (int r = 0; r < 4; ++r) { sqi[r] = s_sqi[ibase + r]; ti[r] = s_ti[ibase + r]; }

    float racc[4] = {0.f, 0.f, 0.f, 0.f};
    float cacc[8] = {0.f, 0.f, 0.f, 0.f, 0.f, 0.f, 0.f, 0.f};
    #pragma unroll
    for (int fj = 0; fj < 8; ++fj) {
        int jl = fj * 16 + lr;
        float sqj = s_sqj[jl];
        int   tj  = s_tj[jl];
        int   gj  = gjb + jl;
        #pragma unroll
        for (int r = 0; r < 4; ++r) {
            int gi = gib + ibase + r;
            float d2 = fmaxf(sqi[r] + sqj - 2.0f * C[fj][r], 0.0f);
            float dist = __builtin_amdgcn_sqrtf(d2);
            float e = __expf(1.0f - dist);
            bool valid = (gi < gj) && (ti[r] != tj) && (d2 > 0.0f);
            e = valid ? e : 0.0f;
            racc[r] += e;
            cacc[fj] += e;
        }
    }

    // row sums: reduce across lr (16 lanes) -> global atomics
    #pragma unroll
    for (int r = 0; r < 4; ++r) {
        racc[r] += __shfl_xor(racc[r], 1);
        racc[r] += __shfl_xor(racc[r], 2);
        racc[r] += __shfl_xor(racc[r], 4);
        racc[r] += __shfl_xor(racc[r], 8);
    }
    if (lr == 0) {
        #pragma unroll
        for (int r = 0; r < 4; ++r) atomicAdd(&rn[gib + ibase + r], racc[r]);
    }
    // col sums: reduce across lg groups within wave, combine 8 waves via LDS
    #pragma unroll
    for (int fj = 0; fj < 8; ++fj) {
        cacc[fj] += __shfl_xor(cacc[fj], 16);
        cacc[fj] += __shfl_xor(cacc[fj], 32);
    }
    if (lg == 0) {
        #pragma unroll
        for (int fj = 0; fj < 8; ++fj) s_cacc[w][fj * 16 + lr] = cacc[fj];
    }
    __syncthreads();
    if (t < 128) {
        float cs = 0.0f;
        #pragma unroll
        for (int ww = 0; ww < 8; ++ww) cs += s_cacc[ww][t];
        if (cs != 0.0f) atomicAdd(&rn[gjb + t], cs);
    }
}

// ---- per-class positive-pair loss; last block finalizes ----
__global__ __launch_bounds__(256) void loss_kernel(
        const unsigned short* __restrict__ Xb, const float* __restrict__ X,
        const float* __restrict__ sq, const float* __restrict__ rn,
        const int* __restrict__ ccnt, const int* __restrict__ list,
        float* __restrict__ acc, unsigned* __restrict__ tick, float* __restrict__ out)
{
    const int c = blockIdx.x;
    int m = ccnt[c]; if (m > CCAP) m = CCAP;
    const int mm = m < MAXM ? m : MAXM;
    const int nfj = (mm + 15) >> 4;            // active 16-col blocks

    __shared__ __align__(16) unsigned short tX[MAXM * DIM];
    __shared__ float sqg[MAXM], rng[MAXM];
    __shared__ int   s_idx[MAXM];
    __shared__ float s_red[16];

    const int t = threadIdx.x;
    const int w = t >> 6, l = t & 63, lr = l & 15, lg = l >> 4;

    if (t < MAXM) s_idx[t] = (t < mm) ? list[c * CCAP + t] : 0;
    __syncthreads();
    if (t < MAXM) {
        int ri = s_idx[t];
        sqg[t] = (t < mm) ? sq[ri] : 0.0f;
        rng[t] = (t < mm) ? rn[ri] : 0.0f;
    }
    // gathered stage: per-lane gather + swizzle source, linear LDS dest
    #pragma unroll
    for (int kk = 0; kk < 8; ++kk) {
        int q = w * 8 + kk;
        int row = q * 4 + (l >> 4);
        if (row < ((mm + 3) & ~3)) {
            int sc = (l & 15) ^ (row & 7);
            gload16(Xb + (size_t)s_idx[row] * DIM + sc * 8, &tX[q * 512]);
        }
    }
    __syncthreads();

    float csum = 0.0f, cpairs = 0.0f;
    // wave w handles rows fi*64 + w*16 .. +16  (all waves active at mm<=64 for fi=0)
    #pragma unroll
    for (int fi = 0; fi < 2; ++fi) {
        const int rowbase = fi * 64 + w * 16;
        if (rowbase < mm) {                              // wave-uniform guard
            f32x4 C[8] = {};
            const int arow = rowbase + lr;
            #pragma unroll
            for (int ks = 0; ks < 4; ++ks) {
                int cb = ks * 4 + lg;
                short8 a = *reinterpret_cast<const short8*>(&tX[arow * DIM + ((cb ^ (arow & 7)) * 8)]);
                #pragma unroll
                for (int fj = 0; fj < 8; ++fj) {
                    if (fj < nfj) {
                        int brow = fj * 16 + lr;
                        short8 bb = *reinterpret_cast<const short8*>(&tX[brow * DIM + ((cb ^ (brow & 7)) * 8)]);
                        C[fj] = __builtin_amdgcn_mfma_f32_16x16x32_bf16(a, bb, C[fj], 0, 0, 0);
                    }
                }
            }
            #pragma unroll
            for (int fj = 0; fj < 8; ++fj) {
                if (fj < nfj) {
                    int q = fj * 16 + lr;
                    #pragma unroll
                    for (int r = 0; r < 4; ++r) {
                        int p = rowbase + lg * 4 + r;
                        if (q < mm && p < q) {
                            float d2 = fmaxf(sqg[p] + sqg[q] - 2.0f * C[fj][r], 0.0f);
                            float dist = __builtin_amdgcn_sqrtf(d2);
                            float J = __logf(rng[p] + rng[q]) + dist;
                            if (J > 0.0f) csum += J * J;
                            cpairs += 1.0f;
                        }
                    }
                }
            }
        }
    }

    // correctness fallback for improbably large classes (fp32, never hot)
    if (m > MAXM) {
        for (int q = MAXM; q < m; ++q) {
            int rq = list[c * CCAP + q];
            float sqq = sq[rq], rnq = rn[rq];
            for (int p = t; p < q; p += 256) {
                int rp = list[c * CCAP + p];
                const float4* xa = reinterpret_cast<const float4*>(X + (size_t)rp * DIM);
                const float4* xb = reinterpret_cast<const float4*>(X + (size_t)rq * DIM);
                float d = 0.0f;
                for (int kq = 0; kq < 32; ++kq) {
                    float4 av = xa[kq], bv = xb[kq];
                    d += av.x * bv.x + av.y * bv.y + av.z * bv.z + av.w * bv.w;
                }
                float d2 = fmaxf(sq[rp] + sqq - 2.0f * d, 0.0f);
                float dist = __builtin_amdgcn_sqrtf(d2);
                float J = __logf(rn[rp] + rnq) + dist;
                if (J > 0.0f) csum += J * J;
                cpairs += 1.0f;
            }
        }
    }

    #pragma unroll
    for (int mr = 1; mr < 64; mr <<= 1) {
        csum   += __shfl_xor(csum, mr);
        cpairs += __shfl_xor(cpairs, mr);
    }
    if (l == 0) { s_red[w] = csum; s_red[8 + w] = cpairs; }
    __syncthreads();
    if (t == 0) {
        float bs = s_red[0] + s_red[1] + s_red[2] + s_red[3];
        float bc = s_red[8] + s_red[9] + s_red[10] + s_red[11];
        atomicAdd(&acc[0], bs);
        atomicAdd(&acc[1], bc);
        __threadfence();
        unsigned old = atomicAdd(tick, 1u);
        if (old == NCLS - 1) {
            float s  = atomicAdd(&acc[0], 0.0f);
            float n2 = atomicAdd(&acc[1], 0.0f);
            out[0] = s / (2.0f * n2);              // len_p = 2 * upper-tri count
        }
    }
}

extern "C" void kernel_launch(void* const* d_in, const int* in_sizes, int n_in,
                              void* d_out, int out_size, void* d_ws, size_t ws_size,
                              hipStream_t stream)
{
    const float* X  = (const float*)d_in[0];
    const int* tgt  = (const int*)d_in[1];
    float* out      = (float*)d_out;

    char* ws = (char*)d_ws;
    unsigned short* Xb = (unsigned short*)ws;                       // 1 MB
    float* sq   = (float*)(ws + (size_t)NROW * DIM * 2);            // 16 KB
    float* rn   = sq + NROW;                                        // 16 KB
    float* acc  = rn + NROW;                                        // 2 floats
    unsigned* tick = (unsigned*)(acc + 4);
    int* ccnt   = (int*)(tick + 4);                                 // 64 ints
    int* list   = ccnt + NCLS;                                      // 128 KB

    prep_kernel<<<NROW / 8, 256, 0, stream>>>(X, Xb, sq, rn, acc, tick, ccnt);
    rowneg_kernel<<<NTILE, 512, 0, stream>>>(Xb, sq, tgt, rn, ccnt, list);
    loss_kernel<<<NCLS, 256, 0, stream>>>(Xb, X, sq, rn, ccnt, list, acc, tick, out);
}